// Round 11
// baseline (144.851 us; speedup 1.0000x reference)
//
#include <hip/hip_runtime.h>
#include <math.h>

#define NB 8
#define NH 512
#define NW 512
#define ANG512 0.01227184630308513f
#define SPEC_D 16384   // per-depth stride of spec_wr/spec_wi (16*16*8*8)

// ---------------------------------------------------------------------------
// transpose-reduce: 256 threads each hold p[16]; result (sum over threads)
// lands in dst[0..15]. tb must hold 128*17 floats.
// ---------------------------------------------------------------------------
__device__ __forceinline__ void treduce16(float* p, float* tb, float* dst, int tid) {
    #pragma unroll
    for (int j = 0; j < 16; ++j) p[j] += __shfl_xor(p[j], 1);
    if (!(tid & 1)) {
        const int s = tid >> 1;               // 0..127
        #pragma unroll
        for (int j = 0; j < 16; ++j) tb[s * 17 + j] = p[j];
    }
    __syncthreads();
    {
        const int q = tid >> 4, g = tid & 15;
        float v = 0.f;
        #pragma unroll
        for (int j = 0; j < 8; ++j) v += tb[(g + 16 * j) * 17 + q];
        #pragma unroll
        for (int m = 1; m < 16; m <<= 1) v += __shfl_xor(v, m, 16);
        if (g == 0) dst[q] = v;
    }
    __syncthreads();
}

// ---------------------------------------------------------------------------
// k_rowdft: one (b,row) per block.
// R[b,row, 0..7]=Re, [8..15]=Im of sum_w x[b,0,row,w] e^{-2pi i ky w/512}
// ---------------------------------------------------------------------------
__global__ __launch_bounds__(256) void k_rowdft(const float* __restrict__ x,
                                                float* __restrict__ R) {
    __shared__ float tb[128 * 17];
    __shared__ float red[16];
    const int tid = threadIdx.x;
    const int b = blockIdx.x >> 9;
    const int row = blockIdx.x & 511;
    const float* xr = x + ((size_t)(b * NH + row)) * NW;
    const float xa = xr[tid], xb = xr[tid + 256];
    const float a = xa + xb, d = xa - xb;   // parity: tw(w+256)=(-1)^k tw(w)

    float p[16];
    float c1, s1;
    __sincosf(ANG512 * (float)tid, &s1, &c1);
    p[0] = a;      p[8] = 0.f;
    p[1] = d * c1; p[9] = -d * s1;
    {
        const float c2k = 2.f * c1;
        float ckm = 1.f, skm = 0.f, ck = c1, sk = s1;
        #pragma unroll
        for (int k = 2; k < 8; ++k) {
            const float cn = fmaf(c2k, ck, -ckm);
            const float sn = fmaf(c2k, sk, -skm);
            ckm = ck; skm = sk; ck = cn; sk = sn;
            const float v = (k & 1) ? d : a;
            p[k] = v * ck;
            p[8 + k] = -v * sk;
        }
    }
    treduce16(p, tb, red, tid);
    if (tid < 16) R[((size_t)(b * NH + row)) * 16 + tid] = red[tid];
}

// ---------------------------------------------------------------------------
// k_modes: grid (b,kx) = 64 blocks.
//  col-DFT of R -> X2d[ky]; X0 = fc0-fold; 3-layer mode recurrence;
//  AH[b,hd,ky,kx] = c_ky * sum_c fc1[c,hd] A[c,ky].
//  block 0 additionally computes gvec/Kvec.
// ---------------------------------------------------------------------------
__global__ __launch_bounds__(256) void k_modes(
        const float* __restrict__ R,
        const float* __restrict__ spec_wr, const float* __restrict__ spec_wi,
        const float* __restrict__ conv_w, const float* __restrict__ conv_b,
        const float* __restrict__ fc0_w, const float* __restrict__ fc0_b,
        const float* __restrict__ fc1_w, const float* __restrict__ fc1_b,
        float* __restrict__ AH, float* __restrict__ gvec, float* __restrict__ Kvec) {
    __shared__ float Wr_s[3][16][16][8];   // 24 KB
    __shared__ float Wi_s[3][16][16][8];   // 24 KB
    __shared__ float tb[128 * 17];
    __shared__ float X2[16];
    __shared__ float Xr[16][8], Xi[16][8];
    __shared__ float Fr[16][8], Fi[16][8];
    __shared__ float Ar[16][8], Ai[16][8];
    __shared__ float Pm[2][256];           // [0]=C2*C1, [1]=C2
    __shared__ float fc1_s[1024];
    __shared__ float ps[64];               // prep scratch (block 0)

    const int tid = threadIdx.x;
    const int bb = blockIdx.x >> 3;
    const int kx = blockIdx.x & 7;

    // ---- stage spectral weights for this kx ----
    {
        const int i = tid >> 4, o = tid & 15;
        #pragma unroll
        for (int d = 0; d < 3; ++d) {
            const size_t base = (size_t)d * SPEC_D + ((size_t)(i * 16 + o) * 64 + kx * 8);
            const float4* pr = (const float4*)(spec_wr + base);
            const float4* pi = (const float4*)(spec_wi + base);
            *(float4*)(&Wr_s[d][i][o][0]) = pr[0];
            *(float4*)(&Wr_s[d][i][o][4]) = pr[1];
            *(float4*)(&Wi_s[d][i][o][0]) = pi[0];
            *(float4*)(&Wi_s[d][i][o][4]) = pi[1];
        }
    }
    // ---- Pm[0] = C2*C1 (in-block), Pm[1] = C2, stage fc1 ----
    {
        const int o = tid >> 4, c = tid & 15;
        float s = 0.f;
        for (int k = 0; k < 16; ++k)
            s += conv_w[512 + o * 16 + k] * conv_w[256 + k * 16 + c];
        Pm[0][tid] = s;
    }
    Pm[1][tid] = conv_w[512 + tid];
    #pragma unroll
    for (int k = 0; k < 4; ++k) fc1_s[tid + k * 256] = fc1_w[tid + k * 256];

    // ---- col-DFT: X2d[ky] = sum_row R[bb,row,ky] e^{-2pi i kx row/512} ----
    float p[16];
    #pragma unroll
    for (int j = 0; j < 16; ++j) p[j] = 0.f;
    #pragma unroll
    for (int r2 = 0; r2 < 2; ++r2) {
        const int row = tid + r2 * 256;
        const float4* rp4 = (const float4*)(R + ((size_t)(bb * NH + row)) * 16);
        const float4 q0 = rp4[0], q1 = rp4[1], q2 = rp4[2], q3 = rp4[3];
        const float re[8] = {q0.x, q0.y, q0.z, q0.w, q1.x, q1.y, q1.z, q1.w};
        const float im[8] = {q2.x, q2.y, q2.z, q2.w, q3.x, q3.y, q3.z, q3.w};
        const int m = (kx * row) & 511;
        float cm, sm;
        __sincosf(ANG512 * (float)m, &sm, &cm);   // e^{-i th m} = (cm, -sm)
        #pragma unroll
        for (int k = 0; k < 8; ++k) {
            p[k]     += re[k] * cm + im[k] * sm;
            p[8 + k] += im[k] * cm - re[k] * sm;
        }
    }
    treduce16(p, tb, X2, tid);   // internal syncs also cover the staging above

    // ---- recurrence: thread = (o,ky), tid < 128 ----
    const bool act = (tid < 128);
    const int o = tid >> 3, ky = tid & 7;
    if (act) {
        const float inv = 1.f / (512.f * 512.f);
        float xr0 = fc0_w[o] * X2[ky] * inv;
        float xi0 = fc0_w[o] * X2[8 + ky] * inv;
        if (kx == 0 && ky == 0) xr0 += fc0_b[o];
        Xr[o][ky] = xr0; Xi[o][ky] = xi0;
        Ar[o][ky] = 0.f; Ai[o][ky] = 0.f;
    }
    __syncthreads();

    for (int dd = 0; dd < 3; ++dd) {
        if (act) {
            float fr = 0.f, fi = 0.f;
            #pragma unroll
            for (int i = 0; i < 16; ++i) {
                const float wre = Wr_s[dd][i][o][ky];
                const float wim = Wi_s[dd][i][o][ky];
                const float xr0 = Xr[i][ky], xi0 = Xi[i][ky];
                fr += xr0 * wre - xi0 * wim;
                fi += xr0 * wim + xi0 * wre;
            }
            Fr[o][ky] = fr; Fi[o][ky] = fi;
        }
        __syncthreads();
        float xnr = 0.f, xni = 0.f;
        if (act) {
            float ar, ai;
            if (dd == 2) {
                ar = Fr[o][ky]; ai = Fi[o][ky];
            } else {
                ar = 0.f; ai = 0.f;
                #pragma unroll
                for (int c = 0; c < 16; ++c) {
                    const float pv = Pm[dd][o * 16 + c];
                    ar = fmaf(pv, Fr[c][ky], ar);
                    ai = fmaf(pv, Fi[c][ky], ai);
                }
            }
            Ar[o][ky] += ar; Ai[o][ky] += ai;
            if (dd < 2) {
                const float fr0 = Fr[o][ky], fi0 = Fi[o][ky];
                if (ky == 0) {
                    if (kx == 0) { xnr = fr0; xni = 0.f; }
                    else         { xnr = 0.5f * fr0; xni = 0.5f * fi0; }
                } else { xnr = fr0; xni = fi0; }
                #pragma unroll
                for (int c = 0; c < 16; ++c) {
                    const float cc = conv_w[dd * 256 + o * 16 + c];
                    xnr = fmaf(cc, Xr[c][ky], xnr);
                    xni = fmaf(cc, Xi[c][ky], xni);
                }
                if (kx == 0 && ky == 0) xnr += conv_b[dd * 16 + o];
            }
        }
        __syncthreads();
        if (act && dd < 2) { Xr[o][ky] = xnr; Xi[o][ky] = xni; }
        __syncthreads();
    }

    // ---- fold fc1 -> AH[b,hd,ky,kx] (interleaved complex) ----
    #pragma unroll
    for (int k2 = 0; k2 < 2; ++k2) {
        const int idx = tid + k2 * 256;      // hd*8 + ky2
        const int hd = idx >> 3, ky2 = idx & 7;
        float ar = 0.f, ai = 0.f;
        #pragma unroll
        for (int c = 0; c < 16; ++c) {
            const float f = fc1_s[c * 64 + hd];
            ar = fmaf(f, Ar[c][ky2], ar);
            ai = fmaf(f, Ai[c][ky2], ai);
        }
        const float ck = (ky2 == 0) ? 1.f : 2.f;    // Hermitian doubling
        const size_t off = ((((size_t)(bb * 64 + hd)) * 8 + ky2) * 8 + kx) * 2;
        AH[off] = ck * ar;
        AH[off + 1] = ck * ai;
    }

    // ---- block 0: gvec = fc1^T(P0*C0*fc0_w); Kvec = fc1_b + fc1^T(evec) ----
    if (blockIdx.x == 0) {
        if (tid < 16) {
            float su = 0.f, sb = 0.f;
            for (int c = 0; c < 16; ++c) {
                su += conv_w[tid * 16 + c] * fc0_w[c];
                sb += conv_w[tid * 16 + c] * fc0_b[c];
            }
            ps[tid] = su; ps[16 + tid] = sb;
        }
        __syncthreads();
        if (tid < 16) {
            float dv = 0.f, ev = conv_b[32 + tid];
            for (int k = 0; k < 16; ++k) {
                dv += Pm[0][tid * 16 + k] * ps[k];
                ev += Pm[0][tid * 16 + k] * (ps[16 + k] + conv_b[k]);
                ev += conv_w[512 + tid * 16 + k] * conv_b[16 + k];
            }
            ps[32 + tid] = dv; ps[48 + tid] = ev;
        }
        __syncthreads();
        if (tid < 64) {
            float g = 0.f, K = fc1_b[tid];
            for (int c = 0; c < 16; ++c) {
                g = fmaf(fc1_w[c * 64 + tid], ps[32 + c], g);
                K = fmaf(fc1_w[c * 64 + tid], ps[48 + c], K);
            }
            gvec[tid] = g; Kvec[tid] = K;
        }
    }
}

// ---------------------------------------------------------------------------
// k_head: 4 rows/block (wave = row), 8 px/thread.
// One WH read serves 8 pixels: quad {w0+128m} via i^ky rotation, and the
// shifted quad {w0+64+128m} via the compile-time e^{i ky pi/4} rotation of
// the SAME tr/ti values.
// __launch_bounds__(256,2): VGPR budget 256 — the 8px body keeps ~55 floats
// live; (256,4)/(256,8) made the allocator spill (VGPR 40/32 observed).
// ---------------------------------------------------------------------------
__global__ __launch_bounds__(256, 2) void k_head(
        const float* __restrict__ x, const float* __restrict__ AH,
        const float* __restrict__ gvec, const float* __restrict__ Kvec,
        const float* __restrict__ fc2_w, const float* __restrict__ fc2_b,
        float* __restrict__ out) {
    __shared__ float WHr[4][512];
    __shared__ float WHi[4][512];

    const int tid = threadIdx.x;
    const int b = blockIdx.x >> 7;       // 1024 blocks total
    const int rp = blockIdx.x & 127;     // group of 4 rows
    const int rl = tid >> 6;             // wave index = local row
    const int row = rp * 4 + rl;
    const int w0 = tid & 63;

    // hoist x loads (coalesced, latency overlapped with WH build)
    const float* xp = x + ((size_t)(b * NH + row)) * NW + w0;
    float xv[8];
    #pragma unroll
    for (int j = 0; j < 8; ++j) xv[j] = xp[j * 64];

    // ---- WH build: 8 entries/thread for this wave's row ----
    {
        float c1, s1;
        __sincosf(ANG512 * (float)row, &s1, &c1);
        float ctr[8], str[8];
        ctr[0] = 1.f; str[0] = 0.f; ctr[1] = c1; str[1] = s1;
        const float c2k = 2.f * c1;
        #pragma unroll
        for (int k = 2; k < 8; ++k) {
            ctr[k] = fmaf(c2k, ctr[k - 1], -ctr[k - 2]);
            str[k] = fmaf(c2k, str[k - 1], -str[k - 2]);
        }
        #pragma unroll
        for (int j = 0; j < 8; ++j) {
            const int idx = w0 + j * 64;     // hd*8 + ky
            const int hd = idx >> 3, ky = idx & 7;
            const float4* ap = (const float4*)(AH + ((size_t)(b * 64 + hd) * 8 + ky) * 16);
            const float4 a0 = ap[0], a1 = ap[1], a2 = ap[2], a3 = ap[3];
            float wr = a0.x, wi = a0.y;      // kx=0
            wr = fmaf(a0.z, ctr[1], wr); wr = fmaf(-a0.w, str[1], wr);
            wi = fmaf(a0.z, str[1], wi); wi = fmaf(a0.w, ctr[1], wi);
            wr = fmaf(a1.x, ctr[2], wr); wr = fmaf(-a1.y, str[2], wr);
            wi = fmaf(a1.x, str[2], wi); wi = fmaf(a1.y, ctr[2], wi);
            wr = fmaf(a1.z, ctr[3], wr); wr = fmaf(-a1.w, str[3], wr);
            wi = fmaf(a1.z, str[3], wi); wi = fmaf(a1.w, ctr[3], wi);
            wr = fmaf(a2.x, ctr[4], wr); wr = fmaf(-a2.y, str[4], wr);
            wi = fmaf(a2.x, str[4], wi); wi = fmaf(a2.y, ctr[4], wi);
            wr = fmaf(a2.z, ctr[5], wr); wr = fmaf(-a2.w, str[5], wr);
            wi = fmaf(a2.z, str[5], wi); wi = fmaf(a2.w, ctr[5], wi);
            wr = fmaf(a3.x, ctr[6], wr); wr = fmaf(-a3.y, str[6], wr);
            wi = fmaf(a3.x, str[6], wi); wi = fmaf(a3.y, ctr[6], wi);
            wr = fmaf(a3.z, ctr[7], wr); wr = fmaf(-a3.w, str[7], wr);
            wi = fmaf(a3.z, str[7], wi); wi = fmaf(a3.w, ctr[7], wi);
            if (ky == 0) wr += Kvec[hd];
            WHr[rl][idx] = wr;
            WHi[rl][idx] = wi;
        }
    }
    __syncthreads();

    // ---- 8 px/thread: w0 + 64*j ----
    {
        float c1, s1;
        __sincosf(ANG512 * (float)w0, &s1, &c1);
        float ct[8], st[8];
        ct[0] = 1.f; st[0] = 0.f; ct[1] = c1; st[1] = s1;
        const float c2k = 2.f * c1;
        #pragma unroll
        for (int k = 2; k < 8; ++k) {
            ct[k] = fmaf(c2k, ct[k - 1], -ct[k - 2]);
            st[k] = fmaf(c2k, st[k - 1], -st[k - 2]);
        }
        const float r2c = 0.70710678118654752f;
        const float* WR = &WHr[rl][0];
        const float* WI = &WHi[rl][0];
        const float fc2b = fc2_b[0];
        float acc[8];
        #pragma unroll
        for (int j = 0; j < 8; ++j) acc[j] = fc2b;

        #pragma unroll 4
        for (int hd = 0; hd < 64; ++hd) {
            const float4* r4 = (const float4*)(WR + hd * 8);
            const float4 wa = r4[0], wb = r4[1];
            const float4* i4 = (const float4*)(WI + hd * 8);
            const float4 va = i4[0], vb = i4[1];
            // tr_k = Re[WH_k e^{ik th}], ti_k = Im[...]
            const float tr0 = wa.x;
            const float tr1 = wa.y * ct[1] - va.y * st[1];
            const float ti1 = wa.y * st[1] + va.y * ct[1];
            const float tr2 = wa.z * ct[2] - va.z * st[2];
            const float ti2 = wa.z * st[2] + va.z * ct[2];
            const float tr3 = wa.w * ct[3] - va.w * st[3];
            const float ti3 = wa.w * st[3] + va.w * ct[3];
            const float tr4 = wb.x * ct[4] - vb.x * st[4];
            const float tr5 = wb.y * ct[5] - vb.y * st[5];
            const float ti5 = wb.y * st[5] + vb.y * ct[5];
            const float tr6 = wb.z * ct[6] - vb.z * st[6];
            const float ti6 = wb.z * st[6] + vb.z * ct[6];
            const float tr7 = wb.w * ct[7] - vb.w * st[7];
            const float ti7 = wb.w * st[7] + vb.w * ct[7];

            const float gh = gvec[hd];
            const float w2 = fc2_w[hd];

            // quad 1: pixels w0 + 128m  (i^ky rotation)
            const float A0 = tr0 + tr4, A2 = tr2 + tr6;
            const float E = A0 + A2, D = A0 - A2;
            const float B13 = (tr1 + tr5) + (tr3 + tr7);
            const float U = (ti1 + ti5) - (ti3 + ti7);
            const float s0 = fmaf(gh, xv[0], E + B13);
            const float s2 = fmaf(gh, xv[2], D - U);
            const float s4 = fmaf(gh, xv[4], E - B13);
            const float s6 = fmaf(gh, xv[6], D + U);
            acc[0] = fmaf(fmaxf(s0, 0.f), w2, acc[0]);
            acc[2] = fmaf(fmaxf(s2, 0.f), w2, acc[2]);
            acc[4] = fmaf(fmaxf(s4, 0.f), w2, acc[4]);
            acc[6] = fmaf(fmaxf(s6, 0.f), w2, acc[6]);

            // quad 2: pixels w0+64+128m  (extra e^{i ky pi/4} rotation)
            const float P = tr0 - tr4, Q = ti6 - ti2;
            const float E2 = P + Q, D2 = P - Q;
            const float B2 = r2c * (((tr1 - ti1) - (tr5 - ti5)) + ((tr7 + ti7) - (tr3 + ti3)));
            const float U2 = r2c * (((tr1 + ti1) - (tr5 + ti5)) - ((tr3 - ti3) + (ti7 - tr7)));
            const float s1p = fmaf(gh, xv[1], E2 + B2);
            const float s3p = fmaf(gh, xv[3], D2 - U2);
            const float s5p = fmaf(gh, xv[5], E2 - B2);
            const float s7p = fmaf(gh, xv[7], D2 + U2);
            acc[1] = fmaf(fmaxf(s1p, 0.f), w2, acc[1]);
            acc[3] = fmaf(fmaxf(s3p, 0.f), w2, acc[3]);
            acc[5] = fmaf(fmaxf(s5p, 0.f), w2, acc[5]);
            acc[7] = fmaf(fmaxf(s7p, 0.f), w2, acc[7]);
        }
        float* op = out + ((size_t)(b * NH + row)) * NW + w0;
        #pragma unroll
        for (int j = 0; j < 8; ++j) op[j * 64] = acc[j];
    }
}

// ---------------------------------------------------------------------------
extern "C" void kernel_launch(void* const* d_in, const int* in_sizes, int n_in,
                              void* d_out, int out_size, void* d_ws, size_t ws_size,
                              hipStream_t stream) {
    const float* x       = (const float*)d_in[0];
    const float* fc0_w   = (const float*)d_in[1];
    const float* fc0_b   = (const float*)d_in[2];
    const float* spec_wr = (const float*)d_in[3];
    const float* spec_wi = (const float*)d_in[4];
    const float* conv_w  = (const float*)d_in[5];
    const float* conv_b  = (const float*)d_in[6];
    const float* fc1_w   = (const float*)d_in[7];
    const float* fc1_b   = (const float*)d_in[8];
    const float* fc2_w   = (const float*)d_in[9];
    const float* fc2_b   = (const float*)d_in[10];
    float* outp = (float*)d_out;

    char* ws = (char*)d_ws;
    float* R  = (float*)ws;                       // 8*512*16 floats = 256 KB
    float* AH = (float*)(ws + 262144);            // 8*64*64*2 floats = 256 KB
    float* gv = (float*)(ws + 524288);            // 64 floats
    float* Kv = (float*)(ws + 524288 + 256);      // 64 floats

    k_rowdft<<<NB * NH, 256, 0, stream>>>(x, R);
    k_modes<<<NB * 8, 256, 0, stream>>>(R, spec_wr, spec_wi, conv_w, conv_b,
                                        fc0_w, fc0_b, fc1_w, fc1_b, AH, gv, Kv);
    k_head<<<NB * 128, 256, 0, stream>>>(x, AH, gv, Kv, fc2_w, fc2_b, outp);
}